// Round 1
// baseline (426.499 us; speedup 1.0000x reference)
//
#include <hip/hip_runtime.h>
#include <hip/hip_bf16.h>

// Problem constants
#define BB   128
#define SS   168
#define DM   128
#define LL   2
#define II   256
#define NN   16
#define RR   8
#define KK   4
#define PP   24
#define MROWS (BB*SS)   // 21504
#define NCH  8          // scan chunks
#define TCH  21         // SS / NCH

typedef __attribute__((ext_vector_type(8))) short bf16x8;
typedef __attribute__((ext_vector_type(4))) float f32x4;

__device__ __forceinline__ float wave_sum(float x) {
#pragma unroll
    for (int off = 32; off > 0; off >>= 1) x += __shfl_xor(x, off);
    return x;
}
__device__ __forceinline__ float siluf(float x) {
    return x / (1.f + __expf(-x));
}
__device__ __forceinline__ float softplusf(float x) {
    return (x > 20.f) ? x : __logf(1.f + __expf(x));
}
// HW packed f32->bf16 (RNE), 2 elems/inst
__device__ __forceinline__ bf16x8 cvt8(const float* f) {
    unsigned u0, u1, u2, u3;
    asm("v_cvt_pk_bf16_f32 %0, %1, %2" : "=v"(u0) : "v"(f[0]), "v"(f[1]));
    asm("v_cvt_pk_bf16_f32 %0, %1, %2" : "=v"(u1) : "v"(f[2]), "v"(f[3]));
    asm("v_cvt_pk_bf16_f32 %0, %1, %2" : "=v"(u2) : "v"(f[4]), "v"(f[5]));
    asm("v_cvt_pk_bf16_f32 %0, %1, %2" : "=v"(u3) : "v"(f[6]), "v"(f[7]));
    union { unsigned u[4]; bf16x8 v; } r;
    r.u[0] = u0; r.u[1] = u1; r.u[2] = u2; r.u[3] = u3;
    return r.v;
}

// ---------------------------------------------------------------------------
// bf16-MFMA GEMM: C[M,N] (+)= A[M,K]@W[N,K]^T (+ A2[M,K2]@W2[N,K2]^T)
//                 (+ bias[n]) (+ r1x[m]*r1w[n])
// A-side fusions (in-register, before bf16 round):
//   rs[m]*cs[k]   : rmsnorm fusion
//   silu(em[m,k]) : gate fusion (em has leading dim lde)
// Structure: BM=32, BN=128, BK=64; 512 threads = 8 waves (2 row x 4 col),
// wave tile 16x32 (acc[2] f32x4). B double-buffered in LDS (1 barrier/tile);
// A fragments loaded DIRECTLY global->reg in MFMA layout (32B/lane).
// Output split: logical col >= nsplit goes to C2 at col-nsplit (both ldc).
// If rso != nullptr (requires gridDim.y==1, N==128): writes
// rso[row] = rsqrt(mean(out_row^2)+eps)  — fused rmsnorm rowscale.
// Requires M%32==0, K%64==0 (and K2%64==0 if A2).
// ---------------------------------------------------------------------------
#define LDB 72
template<bool ACCUM>
__global__ __launch_bounds__(512)
void gemm_mfma(const float* __restrict__ A, const float* __restrict__ W, int K,
               const float* __restrict__ A2, const float* __restrict__ W2, int K2,
               const float* __restrict__ bias,
               const float* __restrict__ r1x, const float* __restrict__ r1w,
               const float* __restrict__ rs, const float* __restrict__ cs,
               const float* __restrict__ em, int lde,
               float* __restrict__ C, float* __restrict__ C2, int nsplit, int ldc,
               float* __restrict__ rso)
{
    __shared__ __align__(16) short Bs[2][128 * LDB];
    __shared__ float red[4][32];
    const int bm = blockIdx.x * 32;
    const int bn = blockIdx.y * 128;
    const int t    = threadIdx.x;
    const int lane = t & 63;
    const int wave = t >> 6;           // 0..7
    const int wr   = wave >> 2;        // 0..1: row half (16 rows each)
    const int wc   = wave & 3;         // 0..3: col quarter (32 cols each)
    const int lrow = lane & 15;
    const int lkg  = (lane >> 4) * 8;  // k sub-offset within fragment

    f32x4 acc[2];
    acc[0] = (f32x4){0.f, 0.f, 0.f, 0.f};
    acc[1] = (f32x4){0.f, 0.f, 0.f, 0.f};

    const int brow = t >> 2;           // B staging: 128 rows
    const int bk   = (t & 3) * 16;     // 16 elems per thread
    const int arow = bm + wr * 16 + lrow;
    const float rsv = rs ? rs[arow] : 1.f;

    float bv[16];
    int cur = 0;

#pragma unroll 1
    for (int pass = 0; pass < 2; ++pass) {
        const float* Ap = pass ? A2 : A;
        const float* Wp = pass ? W2 : W;
        const int    Kp = pass ? K2 : K;
        if (!Ap) continue;
        const float* aptr = Ap + (size_t)arow * Kp + lkg;
        const float* eptr = em ? em + (size_t)arow * lde + lkg : nullptr;
        const float* bptr = Wp + (size_t)(bn + brow) * Kp + bk;

        // prologue: stage k-tile 0 into Bs[cur]
#pragma unroll
        for (int q = 0; q < 4; ++q)
            *(float4*)&bv[q * 4] = *(const float4*)(bptr + q * 4);
        *(bf16x8*)&Bs[cur][brow * LDB + bk]     = cvt8(bv);
        *(bf16x8*)&Bs[cur][brow * LDB + bk + 8] = cvt8(bv + 8);
        __syncthreads();

#pragma unroll 1
        for (int k0 = 0; k0 < Kp; k0 += 64) {
            const int kn = k0 + 64;
            if (kn < Kp) {   // prefetch next B tile to regs
#pragma unroll
                for (int q = 0; q < 4; ++q)
                    *(float4*)&bv[q * 4] = *(const float4*)(bptr + kn + q * 4);
            }
            // A fragments: direct global->reg in MFMA layout
            bf16x8 afr[2];
#pragma unroll
            for (int kk = 0; kk < 2; ++kk) {
                float av[8];
                *(float4*)&av[0] = *(const float4*)(aptr + k0 + kk * 32);
                *(float4*)&av[4] = *(const float4*)(aptr + k0 + kk * 32 + 4);
                if (cs) {
                    const int kb = k0 + kk * 32 + lkg;
                    const float4 c0 = *(const float4*)&cs[kb];
                    const float4 c1 = *(const float4*)&cs[kb + 4];
                    av[0] *= rsv * c0.x; av[1] *= rsv * c0.y;
                    av[2] *= rsv * c0.z; av[3] *= rsv * c0.w;
                    av[4] *= rsv * c1.x; av[5] *= rsv * c1.y;
                    av[6] *= rsv * c1.z; av[7] *= rsv * c1.w;
                }
                if (em) {
                    float ev[8];
                    *(float4*)&ev[0] = *(const float4*)(eptr + k0 + kk * 32);
                    *(float4*)&ev[4] = *(const float4*)(eptr + k0 + kk * 32 + 4);
#pragma unroll
                    for (int j = 0; j < 8; ++j) av[j] *= siluf(ev[j]);
                }
                afr[kk] = cvt8(av);
            }
            // MFMA on current LDS buffer
#pragma unroll
            for (int kk = 0; kk < 2; ++kk) {
#pragma unroll
                for (int n = 0; n < 2; ++n) {
                    const bf16x8 bf = *(const bf16x8*)
                        &Bs[cur][(wc * 32 + n * 16 + lrow) * LDB + kk * 32 + lkg];
                    acc[n] = __builtin_amdgcn_mfma_f32_16x16x32_bf16(afr[kk], bf, acc[n], 0, 0, 0);
                }
            }
            // pack next tile into other buffer
            if (kn < Kp) {
                *(bf16x8*)&Bs[cur ^ 1][brow * LDB + bk]     = cvt8(bv);
                *(bf16x8*)&Bs[cur ^ 1][brow * LDB + bk + 8] = cvt8(bv + 8);
            }
            __syncthreads();
            cur ^= 1;
        }
    }

    // epilogue
    const bool hi = (bn >= nsplit);
    float* __restrict__ Cp = hi ? C2 : C;
    const int cb = bn - (hi ? nsplit : 0);
    float p[4] = {0.f, 0.f, 0.f, 0.f};
#pragma unroll
    for (int r = 0; r < 4; ++r) {
        const int row = bm + wr * 16 + (lane >> 4) * 4 + r;
        const float xl = r1x ? r1x[row] : 0.f;
#pragma unroll
        for (int n = 0; n < 2; ++n) {
            const int col = bn + wc * 32 + n * 16 + lrow;   // logical (bias) col
            float v = acc[n][r];
            if (bias) v += bias[col];
            if (r1x)  v += xl * r1w[col];
            float* cp = &Cp[(size_t)row * ldc + (cb + wc * 32 + n * 16 + lrow)];
            if (ACCUM) v += *cp;
            *cp = v;
            p[r] += v * v;
        }
    }
    if (rso) {   // fused rmsnorm rowscale (block owns all 128 cols of its rows)
#pragma unroll
        for (int m = 1; m < 16; m <<= 1) {
#pragma unroll
            for (int r = 0; r < 4; ++r) p[r] += __shfl_xor(p[r], m);
        }
        if (lrow == 0) {
#pragma unroll
            for (int r = 0; r < 4; ++r)
                red[wc][wr * 16 + (lane >> 4) * 4 + r] = p[r];
        }
        __syncthreads();
        if (t < 32) {
            const float s = red[0][t] + red[1][t] + red[2][t] + red[3][t];
            rso[bm + t] = rsqrtf(s * (1.f / DM) + 1e-5f);
        }
    }
}

// ---------------------------------------------------------------------------
// Causal depthwise conv (K=4) + bias + SiLU. hs is [B,S,I] contiguous.
// ---------------------------------------------------------------------------
__global__ __launch_bounds__(256)
void conv_kernel(const float* __restrict__ hs, const float* __restrict__ cw,
                 const float* __restrict__ cb, float* __restrict__ ut)
{
    const int b = blockIdx.x;
    const int s0 = blockIdx.y * TCH;
    const int i = threadIdx.x;
    const float4 w = *(const float4*)&cw[i * 4];
    const float bi = cb[i];
    const float* hp = hs + (size_t)b * SS * II + i;
    float* up = ut + (size_t)b * SS * II + i;
    float wm3 = (s0 - 3 >= 0) ? hp[(s0 - 3) * II] : 0.f;
    float wm2 = (s0 - 2 >= 0) ? hp[(s0 - 2) * II] : 0.f;
    float wm1 = (s0 - 1 >= 0) ? hp[(s0 - 1) * II] : 0.f;
    for (int s = s0; s < s0 + TCH; ++s) {
        const float cur = hp[s * II];
        float a = fmaf(w.x, wm3, fmaf(w.y, wm2, fmaf(w.z, wm1, fmaf(w.w, cur, bi))));
        up[s * II] = siluf(a);
        wm3 = wm2; wm2 = wm1; wm1 = cur;
    }
}

// ---------------------------------------------------------------------------
// x_proj: sp[row,n] = sum_k ut[row,k]*xw[n,k]   (N=40, K=256) — LDS staged.
// ---------------------------------------------------------------------------
__global__ __launch_bounds__(256)
void xproj_kernel(const float* __restrict__ ut, const float* __restrict__ xw,
                  float* __restrict__ sp)
{
    __shared__ float uts[32][260];
    __shared__ float xwt[40][260];
    const int row0 = blockIdx.x * 32;
    const int t = threadIdx.x;
    {
        const int r = t >> 3, c = t & 7;
#pragma unroll
        for (int e = 0; e < 8; ++e) {
            const float4 v = *(const float4*)&ut[(size_t)(row0 + r) * II + (c + e * 8) * 4];
            *(float4*)&uts[r][(c + e * 8) * 4] = v;
        }
    }
    {
#pragma unroll
        for (int e = 0; e < 40; ++e) xwt[e][t] = xw[e * 256 + t];
    }
    __syncthreads();
    const int r = t >> 3, g = t & 7;
    float acc[5] = {0.f, 0.f, 0.f, 0.f, 0.f};
    for (int k = 0; k < II; k += 4) {
        const float4 u = *(const float4*)&uts[r][k];
#pragma unroll
        for (int j = 0; j < 5; ++j) {
            const float4 w = *(const float4*)&xwt[g * 5 + j][k];
            acc[j] = fmaf(u.w, w.w, fmaf(u.z, w.z, fmaf(u.y, w.y, fmaf(u.x, w.x, acc[j]))));
        }
    }
    float* spo = &sp[(size_t)(row0 + r) * 40 + g * 5];
#pragma unroll
    for (int j = 0; j < 5; ++j) spo[j] = acc[j];
}

// ---------------------------------------------------------------------------
// Scan pass A: per (b, chunk), local scan from zero init.
// Outputs P (cumprod of dA) and q (local final state), layout [b][ch][n][i].
// ---------------------------------------------------------------------------
__global__ __launch_bounds__(256)
void scanA_kernel(const float* __restrict__ ut, const float* __restrict__ sp,
                  const float* __restrict__ dtw, const float* __restrict__ dtb,
                  const float* __restrict__ A_log,
                  float* __restrict__ P, float* __restrict__ q)
{
    __shared__ float lsp[TCH * 40];
    const int b = blockIdx.x;
    const int ch = blockIdx.y;
    const int i = threadIdx.x;
    const int s0 = ch * TCH;
    {
        const float* spp = sp + ((size_t)b * SS + s0) * 40;
        for (int idx = i; idx < TCH * 40; idx += 256) lsp[idx] = spp[idx];
    }
    float dw[8];
    {
        const float4 w0 = *(const float4*)&dtw[i * 8];
        const float4 w1 = *(const float4*)&dtw[i * 8 + 4];
        dw[0]=w0.x; dw[1]=w0.y; dw[2]=w0.z; dw[3]=w0.w;
        dw[4]=w1.x; dw[5]=w1.y; dw[6]=w1.z; dw[7]=w1.w;
    }
    const float bdt = dtb[i];
    float Ar[NN];
#pragma unroll
    for (int n = 0; n < NN; ++n) Ar[n] = -__expf(A_log[i * NN + n]);

    float st[NN], cp[NN];
#pragma unroll
    for (int n = 0; n < NN; ++n) { st[n] = 0.f; cp[n] = 1.f; }

    const float* utp = ut + ((size_t)b * SS + s0) * II + i;
    __syncthreads();

    float uv = utp[0];
    for (int s = 0; s < TCH; ++s) {
        const int sn = (s + 1 < TCH) ? s + 1 : s;
        const float uv_n = utp[sn * II];
        const float* r = &lsp[s * 40];
        const float p0 = fmaf(r[1], dw[1], r[0] * dw[0]);
        const float p1 = fmaf(r[3], dw[3], r[2] * dw[2]);
        const float p2 = fmaf(r[5], dw[5], r[4] * dw[4]);
        const float p3 = fmaf(r[7], dw[7], r[6] * dw[6]);
        const float dtv = softplusf(bdt + (p0 + p1) + (p2 + p3));
        const float du = dtv * uv;
#pragma unroll
        for (int n = 0; n < NN; ++n) {
            const float a = __expf(dtv * Ar[n]);
            st[n] = fmaf(a, st[n], du * r[8 + n]);
            cp[n] *= a;
        }
        uv = uv_n;
    }
    float* Pp = P + (((size_t)b * NCH + ch) * NN) * II + i;
    float* qp = q + (((size_t)b * NCH + ch) * NN) * II + i;
#pragma unroll
    for (int n = 0; n < NN; ++n) {
        Pp[n * II] = cp[n];
        qp[n * II] = st[n];
    }
}

// ---------------------------------------------------------------------------
// Combine: q[ch] <- state BEFORE chunk ch. thread = (b, i).
// ---------------------------------------------------------------------------
__global__ __launch_bounds__(256)
void combine_kernel(const float* __restrict__ P, float* __restrict__ q)
{
    const int b = blockIdx.x;
    const int i = threadIdx.x;
#pragma unroll
    for (int n = 0; n < NN; ++n) {
        float cur = 0.f;
#pragma unroll
        for (int ch = 0; ch < NCH; ++ch) {
            const size_t idx = (((size_t)b * NCH + ch) * NN + n) * II + i;
            const float Pv = P[idx];
            const float qv = q[idx];
            q[idx] = cur;
            cur = fmaf(Pv, cur, qv);
        }
    }
}

// ---------------------------------------------------------------------------
// Scan pass B: full scan with proper init; y = st·C + ut*Dp  (gate applied
// later inside the out_proj GEMM staging).
// ---------------------------------------------------------------------------
__global__ __launch_bounds__(256)
void scanB_kernel(const float* __restrict__ ut, const float* __restrict__ sp,
                  const float* __restrict__ qinit,
                  const float* __restrict__ dtw, const float* __restrict__ dtb,
                  const float* __restrict__ A_log, const float* __restrict__ Dp,
                  float* __restrict__ y)
{
    __shared__ float lsp[TCH * 40];
    const int b = blockIdx.x;
    const int ch = blockIdx.y;
    const int i = threadIdx.x;
    const int s0 = ch * TCH;
    {
        const float* spp = sp + ((size_t)b * SS + s0) * 40;
        for (int idx = i; idx < TCH * 40; idx += 256) lsp[idx] = spp[idx];
    }
    float dw[8];
    {
        const float4 w0 = *(const float4*)&dtw[i * 8];
        const float4 w1 = *(const float4*)&dtw[i * 8 + 4];
        dw[0]=w0.x; dw[1]=w0.y; dw[2]=w0.z; dw[3]=w0.w;
        dw[4]=w1.x; dw[5]=w1.y; dw[6]=w1.z; dw[7]=w1.w;
    }
    const float bdt = dtb[i];
    const float Dv = Dp[i];
    float Ar[NN];
#pragma unroll
    for (int n = 0; n < NN; ++n) Ar[n] = -__expf(A_log[i * NN + n]);

    float st[NN];
    {
        const float* qp = qinit + (((size_t)b * NCH + ch) * NN) * II + i;
#pragma unroll
        for (int n = 0; n < NN; ++n) st[n] = qp[n * II];
    }

    const float* utp = ut + ((size_t)b * SS + s0) * II + i;
    float* yp = y + ((size_t)b * SS + s0) * II + i;
    __syncthreads();

    float uv = utp[0];
    for (int s = 0; s < TCH; ++s) {
        const int sn = (s + 1 < TCH) ? s + 1 : s;
        const float uv_n = utp[sn * II];
        const float* r = &lsp[s * 40];
        const float p0 = fmaf(r[1], dw[1], r[0] * dw[0]);
        const float p1 = fmaf(r[3], dw[3], r[2] * dw[2]);
        const float p2 = fmaf(r[5], dw[5], r[4] * dw[4]);
        const float p3 = fmaf(r[7], dw[7], r[6] * dw[6]);
        const float dtv = softplusf(bdt + (p0 + p1) + (p2 + p3));
        const float du = dtv * uv;
        float y0 = 0.f, y1 = 0.f, y2 = 0.f, y3 = 0.f;
#pragma unroll
        for (int n = 0; n < NN; n += 4) {
            const float a0 = __expf(dtv * Ar[n + 0]);
            const float a1 = __expf(dtv * Ar[n + 1]);
            const float a2 = __expf(dtv * Ar[n + 2]);
            const float a3 = __expf(dtv * Ar[n + 3]);
            st[n + 0] = fmaf(a0, st[n + 0], du * r[8 + n + 0]);
            st[n + 1] = fmaf(a1, st[n + 1], du * r[8 + n + 1]);
            st[n + 2] = fmaf(a2, st[n + 2], du * r[8 + n + 2]);
            st[n + 3] = fmaf(a3, st[n + 3], du * r[8 + n + 3]);
            y0 = fmaf(st[n + 0], r[24 + n + 0], y0);
            y1 = fmaf(st[n + 1], r[24 + n + 1], y1);
            y2 = fmaf(st[n + 2], r[24 + n + 2], y2);
            y3 = fmaf(st[n + 3], r[24 + n + 3], y3);
        }
        yp[s * II] = (y0 + y1) + (y2 + y3) + uv * Dv;
        uv = uv_n;
    }
}

// ---------------------------------------------------------------------------
// Final head: rmsnorm(h[b,S-1,:]) -> layernorm -> fc -> out[b,p]
// ---------------------------------------------------------------------------
__global__ __launch_bounds__(64)
void final_kernel(const float* __restrict__ h, const float* __restrict__ fnw,
                  const float* __restrict__ lnw, const float* __restrict__ lnb,
                  const float* __restrict__ fcw, const float* __restrict__ fcb,
                  float* __restrict__ out)
{
    __shared__ float last[DM];
    const int b = blockIdx.x;
    const int lane = threadIdx.x;
    const float* hp = &h[((size_t)b * SS + (SS - 1)) * DM];
    const float2 v = *(const float2*)&hp[lane * 2];
    const float ss = wave_sum(v.x * v.x + v.y * v.y);
    const float sc = rsqrtf(ss * (1.f / DM) + 1e-5f);
    const float2 fw = *(const float2*)&fnw[lane * 2];
    const float t0 = v.x * sc * fw.x, t1 = v.y * sc * fw.y;
    const float m = wave_sum(t0 + t1) * (1.f / DM);
    const float d0 = t0 - m, d1 = t1 - m;
    const float var = wave_sum(d0 * d0 + d1 * d1) * (1.f / DM);
    const float iv = rsqrtf(var + 1e-5f);
    const float2 lw = *(const float2*)&lnw[lane * 2];
    const float2 lb = *(const float2*)&lnb[lane * 2];
    last[lane * 2]     = d0 * iv * lw.x + lb.x;
    last[lane * 2 + 1] = d1 * iv * lw.y + lb.y;
    __syncthreads();
    if (lane < PP) {
        float a = fcb[lane];
#pragma unroll 8
        for (int d = 0; d < DM; ++d) a = fmaf(last[d], fcw[lane * DM + d], a);
        out[b * PP + lane] = a;
    }
}

// ---------------------------------------------------------------------------
extern "C" void kernel_launch(void* const* d_in, const int* in_sizes, int n_in,
                              void* d_out, int out_size, void* d_ws, size_t ws_size,
                              hipStream_t stream)
{
    (void)in_sizes; (void)n_in; (void)out_size; (void)ws_size;
    const float* x_load = (const float*)d_in[0];
    const float* x_img  = (const float*)d_in[1];
    const float* x_text = (const float*)d_in[2];
    const float* Wl     = (const float*)d_in[3];
    const float* Wi     = (const float*)d_in[4];
    const float* Wt     = (const float*)d_in[5];
    const float* b_fuse = (const float*)d_in[6];
    const float* mnorm_w= (const float*)d_in[7];
    const float* in_w   = (const float*)d_in[8];
    const float* in_b   = (const float*)d_in[9];
    const float* conv_w = (const float*)d_in[10];
    const float* conv_b = (const float*)d_in[11];
    const float* xp_w   = (const float*)d_in[12];
    const float* dt_w   = (const float*)d_in[13];
    const float* dt_b   = (const float*)d_in[14];
    const float* A_log  = (const float*)d_in[15];
    const float* Dp     = (const float*)d_in[16];
    const float* out_w  = (const float*)d_in[17];
    const float* out_b  = (const float*)d_in[18];
    const float* fnorm_w= (const float*)d_in[19];
    const float* ln_w   = (const float*)d_in[20];
    const float* ln_b   = (const float*)d_in[21];
    const float* fc_w   = (const float*)d_in[22];
    const float* fc_b   = (const float*)d_in[23];

    float* ws  = (float*)d_ws;
    float* h     = ws;                              // [21504][128]
    float* ybuf  = h     + (size_t)MROWS * DM;      // [21504][256] (y; P alias)
    float* hs    = ybuf  + (size_t)MROWS * II;      // [21504][256] (q alias)
    float* gate  = hs    + (size_t)MROWS * II;      // [21504][256]
    float* ut    = gate  + (size_t)MROWS * II;      // [21504][256]
    float* sp    = ut    + (size_t)MROWS * II;      // [21504][40]
    float* scale = sp    + (size_t)MROWS * 40;      // [21504]
    float* P     = ybuf;                            // [B][NCH][NN][II] (dead before y written)
    float* q     = hs;                              // [B][NCH][NN][II] (hs dead after conv)

    const int NSP_NONE = 1 << 30;

    // --- feature fusion (text + img + rank-1 load + bias), rowscale fused ---
    gemm_mfma<false><<<dim3(MROWS / 32, 1), 512, 0, stream>>>(
        x_text, Wt, 768, x_img, Wi, 64, b_fuse, x_load, Wl,
        nullptr, nullptr, nullptr, 0,
        h, nullptr, NSP_NONE, DM, scale);

    for (int l = 0; l < LL; ++l) {
        // in_proj (rmsnorm fused via rs/cs), hs+gate in ONE dispatch (N=512):
        // blocks with logical col <  256 -> hs, >= 256 -> gate.
        gemm_mfma<false><<<dim3(MROWS / 32, 4), 512, 0, stream>>>(
            h, in_w + (size_t)l * 2 * II * DM, DM, nullptr, nullptr, 0,
            in_b + (size_t)l * 2 * II, nullptr, nullptr,
            scale, mnorm_w + l * DM, nullptr, 0,
            hs, gate, II, II, nullptr);
        conv_kernel<<<dim3(BB, NCH), 256, 0, stream>>>(
            hs, conv_w + l * II * KK, conv_b + l * II, ut);
        xproj_kernel<<<MROWS / 32, 256, 0, stream>>>(
            ut, xp_w + l * 40 * II, sp);
        scanA_kernel<<<dim3(BB, NCH), 256, 0, stream>>>(
            ut, sp, dt_w + l * II * RR, dt_b + l * II, A_log + l * II * NN, P, q);
        combine_kernel<<<BB, 256, 0, stream>>>(P, q);
        scanB_kernel<<<dim3(BB, NCH), 256, 0, stream>>>(
            ut, sp, q, dt_w + l * II * RR, dt_b + l * II,
            A_log + l * II * NN, Dp + l * II, ybuf);
        // out_proj with y*silu(gate) fused into A staging; next layer's
        // rmsnorm rowscale fused into the epilogue (not needed after l=1).
        gemm_mfma<true><<<dim3(MROWS / 32, 1), 512, 0, stream>>>(
            ybuf, out_w + (size_t)l * DM * II, II, nullptr, nullptr, 0,
            out_b + l * DM, nullptr, nullptr,
            nullptr, nullptr, gate, II,
            h, nullptr, NSP_NONE, DM, (l == 0) ? scale : nullptr);
    }

    final_kernel<<<BB, 64, 0, stream>>>(h, fnorm_w, ln_w, ln_b, fc_w, fc_b,
                                        (float*)d_out);
}

// Round 2
// 363.173 us; speedup vs baseline: 1.1744x; 1.1744x over previous
//
#include <hip/hip_runtime.h>
#include <hip/hip_bf16.h>

// Problem constants
#define BB   128
#define SS   168
#define DM   128
#define LL   2
#define II   256
#define NN   16
#define RR   8
#define KK   4
#define PP   24
#define MROWS (BB*SS)   // 21504
#define NCH  8          // scan chunks
#define TCH  21         // SS / NCH

typedef __attribute__((ext_vector_type(8))) short bf16x8;
typedef __attribute__((ext_vector_type(4))) float f32x4;

__device__ __forceinline__ float wave_sum(float x) {
#pragma unroll
    for (int off = 32; off > 0; off >>= 1) x += __shfl_xor(x, off);
    return x;
}
__device__ __forceinline__ float siluf(float x) {
    return x / (1.f + __expf(-x));
}
__device__ __forceinline__ float softplusf(float x) {
    return (x > 20.f) ? x : __logf(1.f + __expf(x));
}
// HW packed f32->bf16 (RNE), 2 elems/inst
__device__ __forceinline__ bf16x8 cvt8(const float* f) {
    unsigned u0, u1, u2, u3;
    asm("v_cvt_pk_bf16_f32 %0, %1, %2" : "=v"(u0) : "v"(f[0]), "v"(f[1]));
    asm("v_cvt_pk_bf16_f32 %0, %1, %2" : "=v"(u1) : "v"(f[2]), "v"(f[3]));
    asm("v_cvt_pk_bf16_f32 %0, %1, %2" : "=v"(u2) : "v"(f[4]), "v"(f[5]));
    asm("v_cvt_pk_bf16_f32 %0, %1, %2" : "=v"(u3) : "v"(f[6]), "v"(f[7]));
    union { unsigned u[4]; bf16x8 v; } r;
    r.u[0] = u0; r.u[1] = u1; r.u[2] = u2; r.u[3] = u3;
    return r.v;
}

// ---------------------------------------------------------------------------
// bf16-MFMA GEMM: C[M,N] (+)= A[M,K]@W[N,K]^T (+ A2[M,K2]@W2[N,K2]^T)
//                 (+ bias[n]) (+ r1x[m]*r1w[n])
// A-side fusions applied during LDS staging (once per element, pre-round):
//   rs[m]*cs[k]   : rmsnorm fusion
//   silu(em[m,k]) : gate fusion (em leading dim lde)
// Structure: 256 threads = 4 waves (2 row x 2 col); BM=32, BN=128, BK=64.
// A and B double-buffered in LDS -> ONE barrier per 64-K tile; next tile's
// global loads issue before the current tile's MFMAs (latency hidden).
// Output split: logical col >= nsplit goes to C2 at col-nsplit (both ldc).
// If rso != nullptr (requires gridDim.y==1, N==128): writes
// rso[row] = rsqrt(mean(out_row^2)+eps)  — fused rmsnorm rowscale.
// Requires M%32==0, K%64==0 (and K2%64==0 if A2).
// ---------------------------------------------------------------------------
#define LDT 72

#define LOADA(kofs) do {                                                     \
    *(float4*)&av[0] = *(const float4*)(aptr + (kofs));                      \
    *(float4*)&av[4] = *(const float4*)(aptr + (kofs) + 4);                  \
    if (cs) {                                                                \
        *(float4*)&cv[0] = *(const float4*)&cs[(kofs) + ak];                 \
        *(float4*)&cv[4] = *(const float4*)&cs[(kofs) + ak + 4];             \
    }                                                                        \
    if (em) {                                                                \
        *(float4*)&ev[0] = *(const float4*)(eptr + (kofs));                  \
        *(float4*)&ev[4] = *(const float4*)(eptr + (kofs) + 4);              \
    } } while (0)

#define LOADB(kofs) do {                                                     \
    _Pragma("unroll")                                                        \
    for (int q = 0; q < 8; ++q)                                              \
        *(float4*)&bv[q * 4] = *(const float4*)(bptr + (kofs) + q * 4);      \
    } while (0)

#define PACKA(buf) do {                                                      \
    float as_[8];                                                            \
    _Pragma("unroll")                                                        \
    for (int j = 0; j < 8; ++j) {                                            \
        float v_ = av[j];                                                    \
        if (cs) v_ *= rsv * cv[j];                                           \
        if (em) v_ *= siluf(ev[j]);                                          \
        as_[j] = v_;                                                         \
    }                                                                        \
    *(bf16x8*)&Asl[buf][arow * LDT + ak] = cvt8(as_); } while (0)

#define PACKB(buf) do {                                                      \
    _Pragma("unroll")                                                        \
    for (int j = 0; j < 4; ++j)                                              \
        *(bf16x8*)&Bsl[buf][brow * LDT + bk + j * 8] = cvt8(bv + j * 8);     \
    } while (0)

template<bool ACCUM>
__global__ __launch_bounds__(256)
void gemm_mfma(const float* __restrict__ A, const float* __restrict__ W, int K,
               const float* __restrict__ A2, const float* __restrict__ W2, int K2,
               const float* __restrict__ bias,
               const float* __restrict__ r1x, const float* __restrict__ r1w,
               const float* __restrict__ rs, const float* __restrict__ cs,
               const float* __restrict__ em, int lde,
               float* __restrict__ C, float* __restrict__ C2, int nsplit, int ldc,
               float* __restrict__ rso)
{
    __shared__ __align__(16) short Asl[2][32 * LDT];
    __shared__ __align__(16) short Bsl[2][128 * LDT];
    __shared__ float red[2][32];
    const int bm = blockIdx.x * 32;
    const int bn = blockIdx.y * 128;
    const int t    = threadIdx.x;
    const int lane = t & 63;
    const int wave = t >> 6;           // 0..3
    const int wr   = wave >> 1;        // 0..1: row half (16 rows)
    const int wc   = wave & 1;         // 0..1: col half (64 cols)
    const int lrow = lane & 15;
    const int lkg  = (lane >> 4) * 8;

    f32x4 acc[4];
#pragma unroll
    for (int j = 0; j < 4; ++j) acc[j] = (f32x4){0.f, 0.f, 0.f, 0.f};

    const int arow = t >> 3, ak = (t & 7) * 8;    // A stage: 32 rows x 64 k
    const int brow = t >> 1, bk = (t & 1) * 32;   // B stage: 128 rows x 64 k
    const float rsv = rs ? rs[bm + arow] : 1.f;

    float av[8], bv[32], cv[8], ev[8];
    int cur = 0;

#pragma unroll 1
    for (int pass = 0; pass < 2; ++pass) {
        const float* Ap = pass ? A2 : A;
        const float* Wp = pass ? W2 : W;
        const int    Kp = pass ? K2 : K;
        if (!Ap) continue;
        const float* aptr = Ap + (size_t)(bm + arow) * Kp + ak;
        const float* eptr = em ? em + (size_t)(bm + arow) * lde + ak : nullptr;
        const float* bptr = Wp + (size_t)(bn + brow) * Kp + bk;

        // prologue: stage k-tile 0 (latency exposed once per pass)
        LOADA(0); LOADB(0);
        PACKA(cur); PACKB(cur);
        __syncthreads();

#pragma unroll 1
        for (int k0 = 0; k0 < Kp; k0 += 64) {
            const int kn = k0 + 64;
            if (kn < Kp) { LOADA(kn); LOADB(kn); }   // prefetch next tile
            // MFMA on current LDS buffer (hides the prefetch latency)
            const bf16x8 af0 = *(const bf16x8*)&Asl[cur][(wr * 16 + lrow) * LDT + lkg];
            const bf16x8 af1 = *(const bf16x8*)&Asl[cur][(wr * 16 + lrow) * LDT + 32 + lkg];
#pragma unroll
            for (int ni = 0; ni < 4; ++ni) {
                const bf16x8 b0 = *(const bf16x8*)
                    &Bsl[cur][(wc * 64 + ni * 16 + lrow) * LDT + lkg];
                acc[ni] = __builtin_amdgcn_mfma_f32_16x16x32_bf16(af0, b0, acc[ni], 0, 0, 0);
            }
#pragma unroll
            for (int ni = 0; ni < 4; ++ni) {
                const bf16x8 b1 = *(const bf16x8*)
                    &Bsl[cur][(wc * 64 + ni * 16 + lrow) * LDT + 32 + lkg];
                acc[ni] = __builtin_amdgcn_mfma_f32_16x16x32_bf16(af1, b1, acc[ni], 0, 0, 0);
            }
            // pack prefetched tile into the other buffer
            if (kn < Kp) { PACKA(cur ^ 1); PACKB(cur ^ 1); }
            __syncthreads();
            cur ^= 1;
        }
    }

    // epilogue
    const bool hi = (bn >= nsplit);
    float* __restrict__ Cp = hi ? C2 : C;
    const int cb = bn - (hi ? nsplit : 0);
    float p[4] = {0.f, 0.f, 0.f, 0.f};
#pragma unroll
    for (int r = 0; r < 4; ++r) {
        const int row = bm + wr * 16 + (lane >> 4) * 4 + r;
        const float xl = r1x ? r1x[row] : 0.f;
#pragma unroll
        for (int ni = 0; ni < 4; ++ni) {
            const int col = bn + wc * 64 + ni * 16 + lrow;   // logical col
            float v = acc[ni][r];
            if (bias) v += bias[col];
            if (r1x)  v += xl * r1w[col];
            float* cp = &Cp[(size_t)row * ldc + (cb + wc * 64 + ni * 16 + lrow)];
            if (ACCUM) v += *cp;
            *cp = v;
            p[r] += v * v;
        }
    }
    if (rso) {   // fused rmsnorm rowscale (block owns all 128 cols of its rows)
#pragma unroll
        for (int m = 1; m < 16; m <<= 1) {
#pragma unroll
            for (int r = 0; r < 4; ++r) p[r] += __shfl_xor(p[r], m);
        }
        if (lrow == 0) {
#pragma unroll
            for (int r = 0; r < 4; ++r)
                red[wc][wr * 16 + (lane >> 4) * 4 + r] = p[r];
        }
        __syncthreads();
        if (t < 32) {
            const float s = red[0][t] + red[1][t];
            rso[bm + t] = rsqrtf(s * (1.f / DM) + 1e-5f);
        }
    }
}

// ---------------------------------------------------------------------------
// Causal depthwise conv (K=4) + bias + SiLU. hs is [B,S,I] contiguous.
// ---------------------------------------------------------------------------
__global__ __launch_bounds__(256)
void conv_kernel(const float* __restrict__ hs, const float* __restrict__ cw,
                 const float* __restrict__ cb, float* __restrict__ ut)
{
    const int b = blockIdx.x;
    const int s0 = blockIdx.y * TCH;
    const int i = threadIdx.x;
    const float4 w = *(const float4*)&cw[i * 4];
    const float bi = cb[i];
    const float* hp = hs + (size_t)b * SS * II + i;
    float* up = ut + (size_t)b * SS * II + i;
    float wm3 = (s0 - 3 >= 0) ? hp[(s0 - 3) * II] : 0.f;
    float wm2 = (s0 - 2 >= 0) ? hp[(s0 - 2) * II] : 0.f;
    float wm1 = (s0 - 1 >= 0) ? hp[(s0 - 1) * II] : 0.f;
    for (int s = s0; s < s0 + TCH; ++s) {
        const float cur = hp[s * II];
        float a = fmaf(w.x, wm3, fmaf(w.y, wm2, fmaf(w.z, wm1, fmaf(w.w, cur, bi))));
        up[s * II] = siluf(a);
        wm3 = wm2; wm2 = wm1; wm1 = cur;
    }
}

// ---------------------------------------------------------------------------
// x_proj: sp[row,n] = sum_k ut[row,k]*xw[n,k]   (N=40, K=256) — LDS staged.
// ---------------------------------------------------------------------------
__global__ __launch_bounds__(256)
void xproj_kernel(const float* __restrict__ ut, const float* __restrict__ xw,
                  float* __restrict__ sp)
{
    __shared__ float uts[32][260];
    __shared__ float xwt[40][260];
    const int row0 = blockIdx.x * 32;
    const int t = threadIdx.x;
    {
        const int r = t >> 3, c = t & 7;
#pragma unroll
        for (int e = 0; e < 8; ++e) {
            const float4 v = *(const float4*)&ut[(size_t)(row0 + r) * II + (c + e * 8) * 4];
            *(float4*)&uts[r][(c + e * 8) * 4] = v;
        }
    }
    {
#pragma unroll
        for (int e = 0; e < 40; ++e) xwt[e][t] = xw[e * 256 + t];
    }
    __syncthreads();
    const int r = t >> 3, g = t & 7;
    float acc[5] = {0.f, 0.f, 0.f, 0.f, 0.f};
    for (int k = 0; k < II; k += 4) {
        const float4 u = *(const float4*)&uts[r][k];
#pragma unroll
        for (int j = 0; j < 5; ++j) {
            const float4 w = *(const float4*)&xwt[g * 5 + j][k];
            acc[j] = fmaf(u.w, w.w, fmaf(u.z, w.z, fmaf(u.y, w.y, fmaf(u.x, w.x, acc[j]))));
        }
    }
    float* spo = &sp[(size_t)(row0 + r) * 40 + g * 5];
#pragma unroll
    for (int j = 0; j < 5; ++j) spo[j] = acc[j];
}

// ---------------------------------------------------------------------------
// Scan pass A: per (b, chunk), local scan from zero init.
// Outputs P (cumprod of dA) and q (local final state), layout [b][ch][n][i].
// ---------------------------------------------------------------------------
__global__ __launch_bounds__(256)
void scanA_kernel(const float* __restrict__ ut, const float* __restrict__ sp,
                  const float* __restrict__ dtw, const float* __restrict__ dtb,
                  const float* __restrict__ A_log,
                  float* __restrict__ P, float* __restrict__ q)
{
    __shared__ float lsp[TCH * 40];
    const int b = blockIdx.x;
    const int ch = blockIdx.y;
    const int i = threadIdx.x;
    const int s0 = ch * TCH;
    {
        const float* spp = sp + ((size_t)b * SS + s0) * 40;
        for (int idx = i; idx < TCH * 40; idx += 256) lsp[idx] = spp[idx];
    }
    float dw[8];
    {
        const float4 w0 = *(const float4*)&dtw[i * 8];
        const float4 w1 = *(const float4*)&dtw[i * 8 + 4];
        dw[0]=w0.x; dw[1]=w0.y; dw[2]=w0.z; dw[3]=w0.w;
        dw[4]=w1.x; dw[5]=w1.y; dw[6]=w1.z; dw[7]=w1.w;
    }
    const float bdt = dtb[i];
    float Ar[NN];
#pragma unroll
    for (int n = 0; n < NN; ++n) Ar[n] = -__expf(A_log[i * NN + n]);

    float st[NN], cp[NN];
#pragma unroll
    for (int n = 0; n < NN; ++n) { st[n] = 0.f; cp[n] = 1.f; }

    const float* utp = ut + ((size_t)b * SS + s0) * II + i;
    __syncthreads();

    float uv = utp[0];
    for (int s = 0; s < TCH; ++s) {
        const int sn = (s + 1 < TCH) ? s + 1 : s;
        const float uv_n = utp[sn * II];
        const float* r = &lsp[s * 40];
        const float p0 = fmaf(r[1], dw[1], r[0] * dw[0]);
        const float p1 = fmaf(r[3], dw[3], r[2] * dw[2]);
        const float p2 = fmaf(r[5], dw[5], r[4] * dw[4]);
        const float p3 = fmaf(r[7], dw[7], r[6] * dw[6]);
        const float dtv = softplusf(bdt + (p0 + p1) + (p2 + p3));
        const float du = dtv * uv;
#pragma unroll
        for (int n = 0; n < NN; ++n) {
            const float a = __expf(dtv * Ar[n]);
            st[n] = fmaf(a, st[n], du * r[8 + n]);
            cp[n] *= a;
        }
        uv = uv_n;
    }
    float* Pp = P + (((size_t)b * NCH + ch) * NN) * II + i;
    float* qp = q + (((size_t)b * NCH + ch) * NN) * II + i;
#pragma unroll
    for (int n = 0; n < NN; ++n) {
        Pp[n * II] = cp[n];
        qp[n * II] = st[n];
    }
}

// ---------------------------------------------------------------------------
// Combine: q[ch] <- state BEFORE chunk ch. thread = (b, i).
// ---------------------------------------------------------------------------
__global__ __launch_bounds__(256)
void combine_kernel(const float* __restrict__ P, float* __restrict__ q)
{
    const int b = blockIdx.x;
    const int i = threadIdx.x;
#pragma unroll
    for (int n = 0; n < NN; ++n) {
        float cur = 0.f;
#pragma unroll
        for (int ch = 0; ch < NCH; ++ch) {
            const size_t idx = (((size_t)b * NCH + ch) * NN + n) * II + i;
            const float Pv = P[idx];
            const float qv = q[idx];
            q[idx] = cur;
            cur = fmaf(Pv, cur, qv);
        }
    }
}

// ---------------------------------------------------------------------------
// Scan pass B: full scan with proper init; y = st·C + ut*Dp  (gate applied
// later inside the out_proj GEMM staging).
// ---------------------------------------------------------------------------
__global__ __launch_bounds__(256)
void scanB_kernel(const float* __restrict__ ut, const float* __restrict__ sp,
                  const float* __restrict__ qinit,
                  const float* __restrict__ dtw, const float* __restrict__ dtb,
                  const float* __restrict__ A_log, const float* __restrict__ Dp,
                  float* __restrict__ y)
{
    __shared__ float lsp[TCH * 40];
    const int b = blockIdx.x;
    const int ch = blockIdx.y;
    const int i = threadIdx.x;
    const int s0 = ch * TCH;
    {
        const float* spp = sp + ((size_t)b * SS + s0) * 40;
        for (int idx = i; idx < TCH * 40; idx += 256) lsp[idx] = spp[idx];
    }
    float dw[8];
    {
        const float4 w0 = *(const float4*)&dtw[i * 8];
        const float4 w1 = *(const float4*)&dtw[i * 8 + 4];
        dw[0]=w0.x; dw[1]=w0.y; dw[2]=w0.z; dw[3]=w0.w;
        dw[4]=w1.x; dw[5]=w1.y; dw[6]=w1.z; dw[7]=w1.w;
    }
    const float bdt = dtb[i];
    const float Dv = Dp[i];
    float Ar[NN];
#pragma unroll
    for (int n = 0; n < NN; ++n) Ar[n] = -__expf(A_log[i * NN + n]);

    float st[NN];
    {
        const float* qp = qinit + (((size_t)b * NCH + ch) * NN) * II + i;
#pragma unroll
        for (int n = 0; n < NN; ++n) st[n] = qp[n * II];
    }

    const float* utp = ut + ((size_t)b * SS + s0) * II + i;
    float* yp = y + ((size_t)b * SS + s0) * II + i;
    __syncthreads();

    float uv = utp[0];
    for (int s = 0; s < TCH; ++s) {
        const int sn = (s + 1 < TCH) ? s + 1 : s;
        const float uv_n = utp[sn * II];
        const float* r = &lsp[s * 40];
        const float p0 = fmaf(r[1], dw[1], r[0] * dw[0]);
        const float p1 = fmaf(r[3], dw[3], r[2] * dw[2]);
        const float p2 = fmaf(r[5], dw[5], r[4] * dw[4]);
        const float p3 = fmaf(r[7], dw[7], r[6] * dw[6]);
        const float dtv = softplusf(bdt + (p0 + p1) + (p2 + p3));
        const float du = dtv * uv;
        float y0 = 0.f, y1 = 0.f, y2 = 0.f, y3 = 0.f;
#pragma unroll
        for (int n = 0; n < NN; n += 4) {
            const float a0 = __expf(dtv * Ar[n + 0]);
            const float a1 = __expf(dtv * Ar[n + 1]);
            const float a2 = __expf(dtv * Ar[n + 2]);
            const float a3 = __expf(dtv * Ar[n + 3]);
            st[n + 0] = fmaf(a0, st[n + 0], du * r[8 + n + 0]);
            st[n + 1] = fmaf(a1, st[n + 1], du * r[8 + n + 1]);
            st[n + 2] = fmaf(a2, st[n + 2], du * r[8 + n + 2]);
            st[n + 3] = fmaf(a3, st[n + 3], du * r[8 + n + 3]);
            y0 = fmaf(st[n + 0], r[24 + n + 0], y0);
            y1 = fmaf(st[n + 1], r[24 + n + 1], y1);
            y2 = fmaf(st[n + 2], r[24 + n + 2], y2);
            y3 = fmaf(st[n + 3], r[24 + n + 3], y3);
        }
        yp[s * II] = (y0 + y1) + (y2 + y3) + uv * Dv;
        uv = uv_n;
    }
}

// ---------------------------------------------------------------------------
// Final head: rmsnorm(h[b,S-1,:]) -> layernorm -> fc -> out[b,p]
// ---------------------------------------------------------------------------
__global__ __launch_bounds__(64)
void final_kernel(const float* __restrict__ h, const float* __restrict__ fnw,
                  const float* __restrict__ lnw, const float* __restrict__ lnb,
                  const float* __restrict__ fcw, const float* __restrict__ fcb,
                  float* __restrict__ out)
{
    __shared__ float last[DM];
    const int b = blockIdx.x;
    const int lane = threadIdx.x;
    const float* hp = &h[((size_t)b * SS + (SS - 1)) * DM];
    const float2 v = *(const float2*)&hp[lane * 2];
    const float ss = wave_sum(v.x * v.x + v.y * v.y);
    const float sc = rsqrtf(ss * (1.f / DM) + 1e-5f);
    const float2 fw = *(const float2*)&fnw[lane * 2];
    const float t0 = v.x * sc * fw.x, t1 = v.y * sc * fw.y;
    const float m = wave_sum(t0 + t1) * (1.f / DM);
    const float d0 = t0 - m, d1 = t1 - m;
    const float var = wave_sum(d0 * d0 + d1 * d1) * (1.f / DM);
    const float iv = rsqrtf(var + 1e-5f);
    const float2 lw = *(const float2*)&lnw[lane * 2];
    const float2 lb = *(const float2*)&lnb[lane * 2];
    last[lane * 2]     = d0 * iv * lw.x + lb.x;
    last[lane * 2 + 1] = d1 * iv * lw.y + lb.y;
    __syncthreads();
    if (lane < PP) {
        float a = fcb[lane];
#pragma unroll 8
        for (int d = 0; d < DM; ++d) a = fmaf(last[d], fcw[lane * DM + d], a);
        out[b * PP + lane] = a;
    }
}

// ---------------------------------------------------------------------------
extern "C" void kernel_launch(void* const* d_in, const int* in_sizes, int n_in,
                              void* d_out, int out_size, void* d_ws, size_t ws_size,
                              hipStream_t stream)
{
    (void)in_sizes; (void)n_in; (void)out_size; (void)ws_size;
    const float* x_load = (const float*)d_in[0];
    const float* x_img  = (const float*)d_in[1];
    const float* x_text = (const float*)d_in[2];
    const float* Wl     = (const float*)d_in[3];
    const float* Wi     = (const float*)d_in[4];
    const float* Wt     = (const float*)d_in[5];
    const float* b_fuse = (const float*)d_in[6];
    const float* mnorm_w= (const float*)d_in[7];
    const float* in_w   = (const float*)d_in[8];
    const float* in_b   = (const float*)d_in[9];
    const float* conv_w = (const float*)d_in[10];
    const float* conv_b = (const float*)d_in[11];
    const float* xp_w   = (const float*)d_in[12];
    const float* dt_w   = (const float*)d_in[13];
    const float* dt_b   = (const float*)d_in[14];
    const float* A_log  = (const float*)d_in[15];
    const float* Dp     = (const float*)d_in[16];
    const float* out_w  = (const float*)d_in[17];
    const float* out_b  = (const float*)d_in[18];
    const float* fnorm_w= (const float*)d_in[19];
    const float* ln_w   = (const float*)d_in[20];
    const float* ln_b   = (const float*)d_in[21];
    const float* fc_w   = (const float*)d_in[22];
    const float* fc_b   = (const float*)d_in[23];

    float* ws  = (float*)d_ws;
    float* h     = ws;                              // [21504][128]
    float* ybuf  = h     + (size_t)MROWS * DM;      // [21504][256] (y; P alias)
    float* hs    = ybuf  + (size_t)MROWS * II;      // [21504][256] (q alias)
    float* gate  = hs    + (size_t)MROWS * II;      // [21504][256]
    float* ut    = gate  + (size_t)MROWS * II;      // [21504][256]
    float* sp    = ut    + (size_t)MROWS * II;      // [21504][40]
    float* scale = sp    + (size_t)MROWS * 40;      // [21504]
    float* P     = ybuf;                            // [B][NCH][NN][II] (dead before y written)
    float* q     = hs;                              // [B][NCH][NN][II] (hs dead after conv)

    const int NSP_NONE = 1 << 30;

    // --- feature fusion (text + img + rank-1 load + bias), rowscale fused ---
    gemm_mfma<false><<<dim3(MROWS / 32, 1), 256, 0, stream>>>(
        x_text, Wt, 768, x_img, Wi, 64, b_fuse, x_load, Wl,
        nullptr, nullptr, nullptr, 0,
        h, nullptr, NSP_NONE, DM, scale);

    for (int l = 0; l < LL; ++l) {
        // in_proj (rmsnorm fused via rs/cs), hs+gate in ONE dispatch (N=512):
        // blocks with logical col <  256 -> hs, >= 256 -> gate.
        gemm_mfma<false><<<dim3(MROWS / 32, 4), 256, 0, stream>>>(
            h, in_w + (size_t)l * 2 * II * DM, DM, nullptr, nullptr, 0,
            in_b + (size_t)l * 2 * II, nullptr, nullptr,
            scale, mnorm_w + l * DM, nullptr, 0,
            hs, gate, II, II, nullptr);
        conv_kernel<<<dim3(BB, NCH), 256, 0, stream>>>(
            hs, conv_w + l * II * KK, conv_b + l * II, ut);
        xproj_kernel<<<MROWS / 32, 256, 0, stream>>>(
            ut, xp_w + l * 40 * II, sp);
        scanA_kernel<<<dim3(BB, NCH), 256, 0, stream>>>(
            ut, sp, dt_w + l * II * RR, dt_b + l * II, A_log + l * II * NN, P, q);
        combine_kernel<<<BB, 256, 0, stream>>>(P, q);
        scanB_kernel<<<dim3(BB, NCH), 256, 0, stream>>>(
            ut, sp, q, dt_w + l * II * RR, dt_b + l * II,
            A_log + l * II * NN, Dp + l * II, ybuf);
        // out_proj with y*silu(gate) fused into A staging; next layer's
        // rmsnorm rowscale fused into the epilogue (not needed after l=1).
        gemm_mfma<true><<<dim3(MROWS / 32, 1), 256, 0, stream>>>(
            ybuf, out_w + (size_t)l * DM * II, II, nullptr, nullptr, 0,
            out_b + l * DM, nullptr, nullptr,
            nullptr, nullptr, gate, II,
            h, nullptr, NSP_NONE, DM, (l == 0) ? scale : nullptr);
    }

    final_kernel<<<BB, 64, 0, stream>>>(h, fnorm_w, ln_w, ln_b, fc_w, fc_b,
                                        (float*)d_out);
}